// Round 3
// baseline (353.529 us; speedup 1.0000x reference)
//
#include <hip/hip_runtime.h>
#include <cstdint>
#include <cstddef>

#define B_ 64
#define P_ 24564
#define C_ 21
#define N_ 16
#define NPL_ 96          // kF blocks per batch: 96*256 >= P_
#define NTT_ 2           // truths per kT block
#define THRESH_ 0.5f

// ---------------------------------------------------------------- helpers

// async global->LDS, 16 B per lane; LDS dest is wave-uniform base + lane*16
__device__ inline void async_copy16(const float* g, float* l) {
    __builtin_amdgcn_global_load_lds(
        (const __attribute__((address_space(1))) void*)g,
        (__attribute__((address_space(3))) void*)l, 16, 0, 0);
}

// smooth-L1 of (loc row - encoded(truth, prior)), summed over 4 coords
__device__ inline float sl1_encode(float4 ld, float4 pr,
                                   float tx1, float ty1, float tx2, float ty2) {
    float gcx = ((tx1 + tx2) * 0.5f - pr.x) / (0.1f * pr.z);
    float gcy = ((ty1 + ty2) * 0.5f - pr.y) / (0.1f * pr.w);
    float gw  = __logf((tx2 - tx1) / pr.z) / 0.2f;
    float gh  = __logf((ty2 - ty1) / pr.w) / 0.2f;
    float g[4] = {gcx, gcy, gw, gh};
    float l[4] = {ld.x, ld.y, ld.z, ld.w};
    float s = 0.0f;
#pragma unroll
    for (int i = 0; i < 4; i++) {
        float d = l[i] - g[i];
        float ad = fabsf(d);
        s += (ad < 1.0f) ? 0.5f * d * d : ad - 0.5f;
    }
    return s;
}

// ---------------------------------------------------------------- kernels

// kT: global per-(batch,truth) argmax of IoU over ALL priors.
// grid (8, B_) x 256 threads; each block handles NTT_=2 truths; thread t
// covers priors t, t+256, ... (coalesced float4). In-thread strict-> update
// keeps smallest p among bit-equal IoUs; cross-lane: max key then min index
// among ties; cross-wave fold in LDS. Exactly reproduces the old
// (key<<32 | ~p) max semantics (first-occurrence argmax, like jnp.argmax).
__global__ __launch_bounds__(256) void
kT_argmax(const float* __restrict__ priors,
          const float* __restrict__ truths,
          int* __restrict__ sp_g) {
    int b = blockIdx.y, n0 = blockIdx.x * NTT_, t = threadIdx.x;
    int wid = t >> 6, lane = t & 63;
    __shared__ unsigned skk[NTT_ * 4];
    __shared__ int skp[NTT_ * 4];

    float4 tb0 = ((const float4*)truths)[b * N_ + n0];      // uniform
    float4 tb1 = ((const float4*)truths)[b * N_ + n0 + 1];  // uniform
    float at0 = (tb0.z - tb0.x) * (tb0.w - tb0.y);
    float at1 = (tb1.z - tb1.x) * (tb1.w - tb1.y);

    unsigned bk0 = 0u, bk1 = 0u;
    int bp0 = 0, bp1 = 0;
    for (int p = t; p < P_; p += 256) {
        float4 pr = ((const float4*)priors)[p];
        float px1 = pr.x - pr.z * 0.5f, py1 = pr.y - pr.w * 0.5f;
        float px2 = pr.x + pr.z * 0.5f, py2 = pr.y + pr.w * 0.5f;
        float ap = (px2 - px1) * (py2 - py1);
        {
            float lx = fmaxf(tb0.x, px1), ly = fmaxf(tb0.y, py1);
            float rx = fminf(tb0.z, px2), ry = fminf(tb0.w, py2);
            float w = fmaxf(rx - lx, 0.0f), h = fmaxf(ry - ly, 0.0f);
            float inter = w * h;
            float iou = inter / (at0 + ap - inter);
            unsigned k = __float_as_uint(iou);
            if (k > bk0) { bk0 = k; bp0 = p; }
        }
        {
            float lx = fmaxf(tb1.x, px1), ly = fmaxf(tb1.y, py1);
            float rx = fminf(tb1.z, px2), ry = fminf(tb1.w, py2);
            float w = fmaxf(rx - lx, 0.0f), h = fmaxf(ry - ly, 0.0f);
            float inter = w * h;
            float iou = inter / (at1 + ap - inter);
            unsigned k = __float_as_uint(iou);
            if (k > bk1) { bk1 = k; bp1 = p; }
        }
    }
    unsigned m0 = bk0, m1 = bk1;
#pragma unroll
    for (int off = 32; off; off >>= 1) {
        unsigned o0 = __shfl_xor(m0, off); m0 = (o0 > m0) ? o0 : m0;
        unsigned o1 = __shfl_xor(m1, off); m1 = (o1 > m1) ? o1 : m1;
    }
    int q0 = (bk0 == m0) ? bp0 : 0x7FFFFFFF;
    int q1 = (bk1 == m1) ? bp1 : 0x7FFFFFFF;
#pragma unroll
    for (int off = 32; off; off >>= 1) {
        int o0 = __shfl_xor(q0, off); q0 = (o0 < q0) ? o0 : q0;
        int o1 = __shfl_xor(q1, off); q1 = (o1 < q1) ? o1 : q1;
    }
    if (lane == 0) {
        skk[0 * 4 + wid] = m0; skp[0 * 4 + wid] = q0;
        skk[1 * 4 + wid] = m1; skp[1 * 4 + wid] = q1;
    }
    __syncthreads();
    if (t < NTT_) {
        unsigned bm = skk[t * 4];
        int bq = skp[t * 4];
        for (int i = 1; i < 4; i++) {
            unsigned m2 = skk[t * 4 + i];
            int q2 = skp[t * 4 + i];
            if (m2 > bm || (m2 == bm && q2 < bq)) { bm = m2; bq = q2; }
        }
        sp_g[b * N_ + n0 + t] = bq;
    }
}

// kF: FUSED match + loss. Block = 256 priors (1/thread).
// ALL per-truth argmax machinery (96 cross-lane shfl ops/thread on the LDS
// pipe) is GONE — kT computes the global argmax directly. kF's inner loop is
// pure VALU (per-prior best/bn via compares); the only LDS-pipe traffic left
// is the 21 LSE ds_reads. One barrier (staging drain + lb).
__global__ __launch_bounds__(256, 6) void
kF_fused(const float* __restrict__ loc,
         const float* __restrict__ conf,
         const float* __restrict__ priors,
         const float* __restrict__ truths,
         const int* __restrict__ labels,
         float* __restrict__ mine,
         float* __restrict__ part_ll,
         float* __restrict__ part_pce,
         int* __restrict__ part_np) {
    int b = blockIdx.y, bx = blockIdx.x, t = threadIdx.x;
    int wid = t >> 6, lane = t & 63;
    __shared__ float scf[256 * C_];          // 21504 B conf tile
    __shared__ int lb[N_];
    __shared__ float sll[4], spc[4];
    __shared__ int snp[4];

    int base_p = bx * 256;
    int nvalid = min(256, P_ - base_p);      // 256, or 244 in the last block
    int maxf4 = (nvalid * C_) >> 2;
    const float* gtile = conf + ((size_t)b * P_ + base_p) * C_;  // 16B-aligned

    // (1) async staging first: wave k%4 issues instr k; 64 lanes x 16 B
    for (int k = wid; k < 21; k += 4) {
        int f4 = k * 64 + lane;
        int s4 = (f4 < maxf4) ? f4 : (maxf4 - 1);   // clamp: no OOB
        async_copy16(gtile + (size_t)s4 * 4, scf + k * 256);
    }
    if (t < N_) lb[t] = labels[b * N_ + t];  // visible after the barrier

    // (2) match compute overlapping the staging latency (pure VALU now)
    int p0 = base_p + t;
    bool valid = t < nvalid;
    float4 pr = ((const float4*)priors)[valid ? p0 : base_p];
    float px1 = pr.x - pr.z * 0.5f, py1 = pr.y - pr.w * 0.5f;
    float px2 = pr.x + pr.z * 0.5f, py2 = pr.y + pr.w * 0.5f;
    float ap = (px2 - px1) * (py2 - py1);

    float best = -1.0f;
    int bn = 0;
#pragma unroll
    for (int n = 0; n < N_; n++) {
        float4 tb = ((const float4*)truths)[b * N_ + n];   // uniform -> s_load
        float at = (tb.z - tb.x) * (tb.w - tb.y);
        float lx = fmaxf(tb.x, px1), ly = fmaxf(tb.y, py1);
        float rx = fminf(tb.z, px2), ry = fminf(tb.w, py2);
        float w = fmaxf(rx - lx, 0.0f), h = fmaxf(ry - ly, 0.0f);
        float inter = w * h;
        float iou = inter / (at + ap - inter);
        if (iou > best) { best = iou; bn = n; }
    }
    int pos = (valid && best >= THRESH_) ? 1 : 0;

    // (3) one barrier: drains async staging (vmcnt) + lb (lgkm)
    __syncthreads();

    // (4) LSE + loss
    float ll = 0.0f, pce = 0.0f;
    int np = 0;
    if (valid) {
        int cls = pos ? (lb[bn] + 1) : 0;
        float ssum = 0.0f;
#pragma unroll
        for (int i = 0; i < 21; i++) ssum += __expf(scf[t * 21 + i]);
        float g = scf[t * 21 + cls];
        float lca = fmaxf(__logf(ssum) - g, 0.0f);   // >= 0 by clamp

        mine[(size_t)b * P_ + p0] = pos ? 0.0f : lca;  // coalesced dword

        if (pos) {
            np = 1;
            pce = lca;
            float4 ld = ((const float4*)loc)[(size_t)b * P_ + p0];
            float4 tb = ((const float4*)truths)[b * N_ + bn];
            ll = sl1_encode(ld, pr, tb.x, tb.y, tb.z, tb.w);
        }
    }

    for (int off = 32; off; off >>= 1) {
        ll += __shfl_down(ll, off);
        pce += __shfl_down(pce, off);
        np += __shfl_down(np, off);
    }
    if (lane == 0) { sll[wid] = ll; spc[wid] = pce; snp[wid] = np; }
    __syncthreads();
    if (t == 0) {
        float a = 0.0f, cc = 0.0f;
        int q = 0;
        for (int i = 0; i < 4; i++) { a += sll[i]; cc += spc[i]; q += snp[i]; }
        part_ll[b * NPL_ + bx] = a;
        part_pce[b * NPL_ + bx] = cc;
        part_np[b * NPL_ + bx] = q;
    }
}

// kB: one block per batch. Reads sp_g directly (defensively clamped to
// [0,P_) — no-op when kT ran, removes the only conceivable OOB path);
// parallel last-occurrence override deltas; top-k via 31-round bitwise
// threshold search (one barrier/round).
__global__ __launch_bounds__(1024) void
kB_batch(const float* __restrict__ loc,
         const float* __restrict__ conf,
         const float* __restrict__ priors,
         const float* __restrict__ truths,
         const int* __restrict__ labels,
         const float* __restrict__ mine,
         const float* __restrict__ part_ll,
         const float* __restrict__ part_pce,
         const int* __restrict__ part_np,
         const int* __restrict__ sp_g,
         double* __restrict__ bll,
         double* __restrict__ bpc,
         int* __restrict__ bnp) {
    int b = blockIdx.x, t = threadIdx.x, wid = t >> 6, lane = t & 63;
    __shared__ float tr[N_ * 4];
    __shared__ int lb[N_];
    __shared__ int sp[N_];
    __shared__ float sdll, sdpce, sll_s, spc_s;
    __shared__ int sdnp, snp_s;
    __shared__ int scnt2[31];
    __shared__ float wsum[16];
    __shared__ int wcgt[16];

    if (t < N_ * 4) tr[t] = truths[b * N_ * 4 + t];
    if (t < N_) {
        lb[t] = labels[b * N_ + t];
        int pv = sp_g[b * N_ + t];
        sp[t] = (pv < 0) ? 0 : ((pv >= P_) ? (P_ - 1) : pv);   // defensive
    }
    if (t < 31) scnt2[t] = 0;
    if (t == 0) { sdll = 0.f; sdpce = 0.f; sdnp = 0; sll_s = 0.f; spc_s = 0.f; snp_s = 0; }
    __syncthreads();

    if (t < 128) {                               // partial-sum gather, 2 waves
        float a = 0.f, c2 = 0.f;
        int q = 0;
        if (t < NPL_) {
            a = part_ll[b * NPL_ + t];
            c2 = part_pce[b * NPL_ + t];
            q = part_np[b * NPL_ + t];
        }
        for (int off = 32; off; off >>= 1) {
            a += __shfl_down(a, off);
            c2 += __shfl_down(c2, off);
            q += __shfl_down(q, off);
        }
        if (lane == 0) {
            atomicAdd(&sll_s, a);
            atomicAdd(&spc_s, c2);
            atomicAdd(&snp_s, q);
        }
    }
    // override deltas: (t, sp[t]) contributes iff t is the LAST truth
    // mapping to this prior (sequential last-wins semantics).
    if (t < N_) {
        int p = sp[t];
        bool last = true;
        for (int n = t + 1; n < N_; n++) if (sp[n] == p) last = false;
        if (last) {
            int nf = t;
            float4 pr = ((const float4*)priors)[p];
            float px1 = pr.x - pr.z * 0.5f, py1 = pr.y - pr.w * 0.5f;
            float px2 = pr.x + pr.z * 0.5f, py2 = pr.y + pr.w * 0.5f;
            float ap = (px2 - px1) * (py2 - py1);
            float best = -1.0f;
            int bti = 0;
            for (int n = 0; n < N_; n++) {
                float tx1 = tr[n * 4], ty1 = tr[n * 4 + 1];
                float tx2 = tr[n * 4 + 2], ty2 = tr[n * 4 + 3];
                float at = (tx2 - tx1) * (ty2 - ty1);
                float lx = fmaxf(tx1, px1), ly = fmaxf(ty1, py1);
                float rx = fminf(tx2, px2), ry = fminf(ty2, py2);
                float w = fmaxf(rx - lx, 0.0f), h = fmaxf(ry - ly, 0.0f);
                float inter = w * h;
                float iou = inter / (at + ap - inter);
                if (iou > best) { best = iou; bti = n; }
            }
            int pos_old = (best >= THRESH_) ? 1 : 0;
            const float* cp = conf + ((size_t)b * P_ + p) * C_;
            float ssum = 0.0f;
            for (int j = 0; j < C_; j++) ssum += __expf(cp[j]);
            float lse = __logf(ssum);
            float4 ld = ((const float4*)loc)[(size_t)b * P_ + p];
            float dll = sl1_encode(ld, pr, tr[nf * 4], tr[nf * 4 + 1],
                                   tr[nf * 4 + 2], tr[nf * 4 + 3]);
            float dpce = lse - cp[lb[nf] + 1];
            int dnp = 1 - pos_old;
            if (pos_old) {
                dll -= sl1_encode(ld, pr, tr[bti * 4], tr[bti * 4 + 1],
                                  tr[bti * 4 + 2], tr[bti * 4 + 3]);
                dpce -= lse - cp[lb[bti] + 1];
            }
            atomicAdd(&sdll, dll);
            atomicAdd(&sdpce, dpce);
            atomicAdd(&sdnp, dnp);
        }
    }

    // per-thread override bitmask + register-cached values
    unsigned omask = 0;
#pragma unroll
    for (int n = 0; n < N_; n++) {
        int p = sp[n];
        if ((p & 1023) == t) omask |= 1u << (p >> 10);
    }
    const float* v = mine + (size_t)b * P_;
    int nel = (t < (P_ - 23 * 1024)) ? 24 : 23;
    float xv[24];
#pragma unroll
    for (int i = 0; i < 24; i++) {
        float x = 0.0f;
        if (i < nel) x = v[t + (i << 10)];
        if ((omask >> i) & 1) x = 0.0f;          // overridden -> positive -> 0
        xv[i] = x;
    }
    __syncthreads();                             // sdnp/snp_s complete
    int np = snp_s + sdnp;
    int k = np * 3;
    if (k > P_ - 1) k = P_ - 1;

    // bitwise threshold search: T ends as the k-th largest bit pattern.
    unsigned T = 0u;
    for (int bpos = 30; bpos >= 0; bpos--) {
        unsigned cand = T | (1u << bpos);
        int c = 0;
#pragma unroll
        for (int i = 0; i < 24; i++)
            if (__float_as_uint(xv[i]) >= cand) c++;
        for (int off = 32; off; off >>= 1) c += __shfl_down(c, off);
        if (lane == 0) atomicAdd(&scnt2[30 - bpos], c);
        __syncthreads();
        int tot = scnt2[30 - bpos];
        T = (tot >= k) ? cand : T;
    }

    float psum = 0.0f;
    int cgt = 0;
#pragma unroll
    for (int i = 0; i < 24; i++) {
        if (__float_as_uint(xv[i]) > T) { psum += xv[i]; cgt++; }
    }
    for (int off = 32; off; off >>= 1) {
        psum += __shfl_down(psum, off);
        cgt += __shfl_down(cgt, off);
    }
    if (lane == 0) { wsum[wid] = psum; wcgt[wid] = cgt; }
    __syncthreads();
    if (t == 0) {
        float s2 = 0.0f;
        int cg = 0;
        for (int i = 0; i < 16; i++) { s2 += wsum[i]; cg += wcgt[i]; }
        int skrem = k - cg;                      // >= 0 by construction
        double tot = (double)s2 + (double)skrem * (double)__uint_as_float(T);
        bll[b] = (double)(sll_s + sdll);
        bpc[b] = (double)(spc_s + sdpce) + tot;
        bnp[b] = np;
    }
}

// kC: final 64-wide reduce.
__global__ void kC_final(const double* __restrict__ bll,
                         const double* __restrict__ bpc,
                         const int* __restrict__ bnp,
                         float* __restrict__ out) {
    int t = threadIdx.x;  // 64 threads
    double a = bll[t], c = bpc[t];
    int n = bnp[t];
    for (int off = 32; off; off >>= 1) {
        a += __shfl_down(a, off);
        c += __shfl_down(c, off);
        n += __shfl_down(n, off);
    }
    if (t == 0) {
        double dn = (double)n;
        out[0] = (float)(a / dn);
        out[1] = (float)(c / dn);
    }
}

// ---------------------------------------------------------------- launch

extern "C" void kernel_launch(void* const* d_in, const int* in_sizes, int n_in,
                              void* d_out, int out_size, void* d_ws, size_t ws_size,
                              hipStream_t stream) {
    const float* loc    = (const float*)d_in[0];
    const float* conf   = (const float*)d_in[1];
    const float* priors = (const float*)d_in[2];
    const float* truths = (const float*)d_in[3];
    const int*   labels = (const int*)d_in[4];
    float* out = (float*)d_out;

    char* ws = (char*)d_ws;
    // layout:
    //   [0       .. 4096)     sp_g: 64*16 ints (global best prior per truth)
    //   [786432  .. 811008)   part_ll:  96*64 floats
    //   [811008  .. 835584)   part_pce: 96*64 floats
    //   [835584  .. 860160)   part_np:  96*64 ints
    //   [860160  .. 860672)   bll: 64 doubles
    //   [860672  .. 861184)   bpc: 64 doubles
    //   [861184  .. 861440)   bnp: 64 ints
    //   [1048576 .. 7336960)  mine: B*P floats
    int*    sp_g     = (int*)(ws);
    float*  part_ll  = (float*)(ws + 786432);
    float*  part_pce = (float*)(ws + 811008);
    int*    part_np  = (int*)(ws + 835584);
    double* bll      = (double*)(ws + 860160);
    double* bpc      = (double*)(ws + 860672);
    int*    bnp      = (int*)(ws + 861184);
    float*  mine     = (float*)(ws + 1048576);

    hipLaunchKernelGGL(kT_argmax, dim3(N_ / NTT_, B_), dim3(256), 0, stream,
                       priors, truths, sp_g);
    hipLaunchKernelGGL(kF_fused, dim3(NPL_, B_), dim3(256), 0, stream,
                       loc, conf, priors, truths, labels,
                       mine, part_ll, part_pce, part_np);
    hipLaunchKernelGGL(kB_batch, dim3(B_), dim3(1024), 0, stream,
                       loc, conf, priors, truths, labels, mine,
                       part_ll, part_pce, part_np, sp_g, bll, bpc, bnp);
    hipLaunchKernelGGL(kC_final, dim3(1), dim3(64), 0, stream, bll, bpc, bnp, out);
}

// Round 4
// 232.474 us; speedup vs baseline: 1.5207x; 1.5207x over previous
//
#include <hip/hip_runtime.h>
#include <cstdint>
#include <cstddef>

#define B_ 64
#define P_ 24564
#define C_ 21
#define N_ 16
#define NPL_ 96          // kF blocks per batch: 96*256 >= P_
#define THRESH_ 0.5f

// ---------------------------------------------------------------- helpers

// async global->LDS, 16 B per lane; LDS dest is wave-uniform base + lane*16
__device__ inline void async_copy16(const float* g, float* l) {
    __builtin_amdgcn_global_load_lds(
        (const __attribute__((address_space(1))) void*)g,
        (__attribute__((address_space(3))) void*)l, 16, 0, 0);
}

// smooth-L1 of (loc row - encoded(truth, prior)), summed over 4 coords
__device__ inline float sl1_encode(float4 ld, float4 pr,
                                   float tx1, float ty1, float tx2, float ty2) {
    float gcx = ((tx1 + tx2) * 0.5f - pr.x) / (0.1f * pr.z);
    float gcy = ((ty1 + ty2) * 0.5f - pr.y) / (0.1f * pr.w);
    float gw  = __logf((tx2 - tx1) / pr.z) / 0.2f;
    float gh  = __logf((ty2 - ty1) / pr.w) / 0.2f;
    float g[4] = {gcx, gcy, gw, gh};
    float l[4] = {ld.x, ld.y, ld.z, ld.w};
    float s = 0.0f;
#pragma unroll
    for (int i = 0; i < 4; i++) {
        float d = l[i] - g[i];
        float ad = fabsf(d);
        s += (ad < 1.0f) ? 0.5f * d * d : ad - 0.5f;
    }
    return s;
}

// suffix-rank scan over hist[0..M): executed by ONE wave (64 lanes).
// Finds bin B with count(bins > B) < kk <= count(bins >= B); rem = kk - count(>B).
__device__ inline void scan_hist(const int* h, int M, int kk,
                                 int* outB, int* outR) {
    int lane = threadIdx.x & 63;
    int CH = M >> 6;                      // bins per lane
    int base = M - (lane + 1) * CH;       // lane 0 = topmost chunk
    int s = 0;
    for (int j = 0; j < CH; j++) s += h[base + j];
    int incl = s;
#pragma unroll
    for (int off = 1; off < 64; off <<= 1) {
        int v = __shfl_up(incl, off);
        if (lane >= off) incl += v;
    }
    int excl = incl - s;                  // count in bins above this chunk
    if (excl < kk && excl + s >= kk) {    // exactly one lane (s>0 there)
        int acc = excl;
        for (int bin = base + CH - 1; bin >= base; bin--) {
            int c = h[bin];
            if (acc + c >= kk) { *outB = bin; *outR = kk - acc; break; }
            acc += c;
        }
    }
}

// ---------------------------------------------------------------- kernels

// kF: FUSED match + loss. Block = 256 priors; WAVE-AUTONOMOUS staging.
// Each wave stages its OWN 64 priors' conf rows (5376 B) into a private
// 6144 B LDS slice via 6 global_load_lds, then drains with a wave-local
// s_waitcnt vmcnt(0) — NO block barrier between staging and LSE, so waves
// (and resident blocks) no longer convoy on the slowest cache line.
// Argmax kept in-register (r1 form: 6 shfl_xor + ballot per truth) — the
// r3 slim-loop variant spilled to scratch (173 MB writebacks). Labels fold
// into the IoU loop (bl cndmask); single barrier at kernel end serves the
// swk fold + partial reduce.
__global__ __launch_bounds__(256, 6) void
kF_fused(const float* __restrict__ loc,
         const float* __restrict__ conf,
         const float* __restrict__ priors,
         const float* __restrict__ truths,
         const int* __restrict__ labels,
         float* __restrict__ mine,
         float* __restrict__ part_ll,
         float* __restrict__ part_pce,
         int* __restrict__ part_np,
         unsigned long long* __restrict__ part_key) {
    int b = blockIdx.y, bx = blockIdx.x, t = threadIdx.x;
    int wid = t >> 6, lane = t & 63;
    __shared__ float scf[4 * 1536];          // 4 wave slices x 6144 B
    __shared__ unsigned long long swk[N_ * 4];
    __shared__ float sll[4], spc[4];
    __shared__ int snp[4];

    int base_p = bx * 256;
    int nvalid = min(256, P_ - base_p);      // 256, or 244 in the last block
    int maxf4 = (nvalid * C_) >> 2;          // valid float4 count, block tile
    const float* gtile = conf + ((size_t)b * P_ + base_p) * C_;  // 16B-aligned

    // prior first (oldest vmem op -> its wait leaves staging in flight)
    int p0 = base_p + t;
    bool valid = t < nvalid;
    float4 pr = ((const float4*)priors)[valid ? p0 : base_p];
    float px1 = pr.x - pr.z * 0.5f, py1 = pr.y - pr.w * 0.5f;
    float px2 = pr.x + pr.z * 0.5f, py2 = pr.y + pr.w * 0.5f;
    float ap = (px2 - px1) * (py2 - py1);

    // wave-private staging: 6 x 1024 B into slice [wid*6144, wid*6144+6144)
    float* slice = scf + wid * 1536;
    int wf4 = wid * 336;                     // wave's first float4 in tile
#pragma unroll
    for (int i = 0; i < 6; i++) {
        int f4 = wf4 + i * 64 + lane;
        int s4 = (f4 < maxf4) ? f4 : (maxf4 - 1);   // clamp: no OOB
        async_copy16(gtile + (size_t)s4 * 4, slice + i * 256);
    }

    // IoU loop over 16 truths (uniform s_loads), overlapping staging
    float best = -1.0f;
    int bn = 0, bl = 0;
#pragma unroll
    for (int n = 0; n < N_; n++) {
        float4 tb = ((const float4*)truths)[b * N_ + n];   // uniform
        int ln = labels[b * N_ + n];                       // uniform
        float at = (tb.z - tb.x) * (tb.w - tb.y);
        float lx = fmaxf(tb.x, px1), ly = fmaxf(tb.y, py1);
        float rx = fminf(tb.z, px2), ry = fminf(tb.w, py2);
        float w = fmaxf(rx - lx, 0.0f), h = fmaxf(ry - ly, 0.0f);
        float inter = w * h;
        float iou = inter / (at + ap - inter);
        if (iou > best) { best = iou; bn = n; bl = ln; }

        // in-register wave argmax (iou>=0 -> bits order-isomorphic)
        unsigned k32 = valid ? __float_as_uint(iou) : 0u;
        unsigned m = k32;
#pragma unroll
        for (int off = 32; off; off >>= 1) {
            unsigned o = __shfl_xor(m, off);
            m = (o > m) ? o : m;
        }
        unsigned long long msk = __ballot(k32 == m);
        int wl = (int)__ffsll(msk) - 1;      // smallest lane = smallest prior
        if (lane == 0)
            swk[n * 4 + wid] = ((unsigned long long)m << 32) |
                               (unsigned)~(unsigned)(base_p + (wid << 6) + wl);
    }
    int pos = (valid && best >= THRESH_) ? 1 : 0;

    // wave-local drain of THIS wave's staging loads (no block barrier)
    asm volatile("s_waitcnt vmcnt(0)" ::: "memory");

    // LSE + loss from the wave-private slice
    float ll = 0.0f, pce = 0.0f;
    int np = 0;
    if (valid) {
        int cls = pos ? (bl + 1) : 0;
        const float* row = scf + wid * 1536 + lane * 21;
        float ssum = 0.0f;
#pragma unroll
        for (int i = 0; i < 21; i++) ssum += __expf(row[i]);
        float g = row[cls];
        float lca = fmaxf(__logf(ssum) - g, 0.0f);   // >= 0 by clamp

        mine[(size_t)b * P_ + p0] = pos ? 0.0f : lca;  // coalesced dword

        if (pos) {
            np = 1;
            pce = lca;
            float4 ld = ((const float4*)loc)[(size_t)b * P_ + p0];
            float4 tb = ((const float4*)truths)[b * N_ + bn];
            ll = sl1_encode(ld, pr, tb.x, tb.y, tb.z, tb.w);
        }
    }

    for (int off = 32; off; off >>= 1) {
        ll += __shfl_down(ll, off);
        pce += __shfl_down(pce, off);
        np += __shfl_down(np, off);
    }
    if (lane == 0) { sll[wid] = ll; spc[wid] = pce; snp[wid] = np; }

    // single block barrier: swk + partials all visible
    __syncthreads();
    if (t < N_) {
        unsigned long long bk = swk[t * 4];
#pragma unroll
        for (int i = 1; i < 4; i++) {
            unsigned long long o = swk[t * 4 + i];
            bk = (o > bk) ? o : bk;
        }
        part_key[(size_t)(b * NPL_ + bx) * N_ + t] = bk;
    }
    if (t == 0) {
        float a = 0.0f, cc = 0.0f;
        int q = 0;
        for (int i = 0; i < 4; i++) { a += sll[i]; cc += spc[i]; q += snp[i]; }
        part_ll[b * NPL_ + bx] = a;
        part_pce[b * NPL_ + bx] = cc;
        part_np[b * NPL_ + bx] = q;
    }
}

// kB: one block per batch. Argmax-partials reduce; last-occurrence override
// deltas; top-k threshold via 3-STAGE RADIX HISTOGRAM (bits>>20 over 2048
// bins with 4 replicas to cut LDS-atomic contention, then 10+10 low bits)
// instead of the 31-round bitwise search (31 heavy barriers -> ~8 cheap
// ones). T = k-th largest bit pattern, identical semantics.
__global__ __launch_bounds__(1024) void
kB_batch(const float* __restrict__ loc,
         const float* __restrict__ conf,
         const float* __restrict__ priors,
         const float* __restrict__ truths,
         const int* __restrict__ labels,
         const float* __restrict__ mine,
         const float* __restrict__ part_ll,
         const float* __restrict__ part_pce,
         const int* __restrict__ part_np,
         const unsigned long long* __restrict__ part_key,
         double* __restrict__ bll,
         double* __restrict__ bpc,
         int* __restrict__ bnp) {
    int b = blockIdx.x, t = threadIdx.x, wid = t >> 6, lane = t & 63;
    __shared__ float tr[N_ * 4];
    __shared__ int lb[N_];
    __shared__ unsigned long long skmax[N_];
    __shared__ int sp[N_];
    __shared__ float sdll, sdpce, sll_s, spc_s;
    __shared__ int sdnp, snp_s;
    __shared__ int hist[4 * 2048];           // stage-1 replicas (32 KB)
    __shared__ int hist2[1024];
    __shared__ int hist3[1024];
    __shared__ int sB[3], sR[3];
    __shared__ float wsum[16];
    __shared__ int wcgt[16];

    if (t < N_ * 4) tr[t] = truths[b * N_ * 4 + t];
    if (t < N_) { lb[t] = labels[b * N_ + t]; skmax[t] = 0ull; }
#pragma unroll
    for (int i = 0; i < 8; i++) hist[t + (i << 10)] = 0;
    hist2[t] = 0;
    hist3[t] = 0;
    if (t == 0) { sdll = 0.f; sdpce = 0.f; sdnp = 0; sll_s = 0.f; spc_s = 0.f; snp_s = 0; }
    __syncthreads();
    // phase 1: parallel reduce of 96 argmax partials per truth (16x16 threads)
    if (t < 256) {
        int n = t & 15, j = t >> 4;
        unsigned long long bk = 0ull;
        for (int i = j; i < NPL_; i += 16) {
            unsigned long long k = part_key[(size_t)(b * NPL_ + i) * N_ + n];
            bk = (k > bk) ? k : bk;
        }
        atomicMax(&skmax[n], bk);
    }
    if (t < 128) {                               // partial-sum gather, 2 waves
        float a = 0.f, c2 = 0.f;
        int q = 0;
        if (t < NPL_) {
            a = part_ll[b * NPL_ + t];
            c2 = part_pce[b * NPL_ + t];
            q = part_np[b * NPL_ + t];
        }
        for (int off = 32; off; off >>= 1) {
            a += __shfl_down(a, off);
            c2 += __shfl_down(c2, off);
            q += __shfl_down(q, off);
        }
        if (lane == 0) {
            atomicAdd(&sll_s, a);
            atomicAdd(&spc_s, c2);
            atomicAdd(&snp_s, q);
        }
    }
    __syncthreads();
    if (t < N_) sp[t] = (int)~(unsigned)(skmax[t] & 0xFFFFFFFFull);
    __syncthreads();
    // override deltas: (t, sp[t]) contributes iff t is the LAST truth
    // mapping to this prior (sequential last-wins semantics).
    if (t < N_) {
        int p = sp[t];
        bool last = true;
        for (int n = t + 1; n < N_; n++) if (sp[n] == p) last = false;
        if (last) {
            int nf = t;
            float4 pr = ((const float4*)priors)[p];
            float px1 = pr.x - pr.z * 0.5f, py1 = pr.y - pr.w * 0.5f;
            float px2 = pr.x + pr.z * 0.5f, py2 = pr.y + pr.w * 0.5f;
            float ap = (px2 - px1) * (py2 - py1);
            float best = -1.0f;
            int bti = 0;
            for (int n = 0; n < N_; n++) {
                float tx1 = tr[n * 4], ty1 = tr[n * 4 + 1];
                float tx2 = tr[n * 4 + 2], ty2 = tr[n * 4 + 3];
                float at = (tx2 - tx1) * (ty2 - ty1);
                float lx = fmaxf(tx1, px1), ly = fmaxf(ty1, py1);
                float rx = fminf(tx2, px2), ry = fminf(ty2, py2);
                float w = fmaxf(rx - lx, 0.0f), h = fmaxf(ry - ly, 0.0f);
                float inter = w * h;
                float iou = inter / (at + ap - inter);
                if (iou > best) { best = iou; bti = n; }
            }
            int pos_old = (best >= THRESH_) ? 1 : 0;
            const float* cp = conf + ((size_t)b * P_ + p) * C_;
            float ssum = 0.0f;
            for (int j = 0; j < C_; j++) ssum += __expf(cp[j]);
            float lse = __logf(ssum);
            float4 ld = ((const float4*)loc)[(size_t)b * P_ + p];
            float dll = sl1_encode(ld, pr, tr[nf * 4], tr[nf * 4 + 1],
                                   tr[nf * 4 + 2], tr[nf * 4 + 3]);
            float dpce = lse - cp[lb[nf] + 1];
            int dnp = 1 - pos_old;
            if (pos_old) {
                dll -= sl1_encode(ld, pr, tr[bti * 4], tr[bti * 4 + 1],
                                  tr[bti * 4 + 2], tr[bti * 4 + 3]);
                dpce -= lse - cp[lb[bti] + 1];
            }
            atomicAdd(&sdll, dll);
            atomicAdd(&sdpce, dpce);
            atomicAdd(&sdnp, dnp);
        }
    }

    // per-thread override bitmask + register-cached values
    unsigned omask = 0;
#pragma unroll
    for (int n = 0; n < N_; n++) {
        int p = sp[n];
        if ((p & 1023) == t) omask |= 1u << (p >> 10);
    }
    const float* v = mine + (size_t)b * P_;
    int nel = (t < (P_ - 23 * 1024)) ? 24 : 23;
    float xv[24];
#pragma unroll
    for (int i = 0; i < 24; i++) {
        float x = 0.0f;
        if (i < nel) x = v[t + (i << 10)];
        if ((omask >> i) & 1) x = 0.0f;          // overridden -> positive -> 0
        xv[i] = x;
    }

    // stage-1 histogram accumulate (4 replicas by wave group)
    int rep = (wid & 3) << 11;
#pragma unroll
    for (int i = 0; i < 24; i++) {
        if (i < nel) {
            unsigned bb = __float_as_uint(xv[i]);
            atomicAdd(&hist[rep + (bb >> 20)], 1);
        }
    }
    __syncthreads();                             // hist replicas + snp_s ready
    // merge replicas into replica 0 (each bin owned by one thread)
    {
        int h0 = hist[t] + hist[t + 2048] + hist[t + 4096] + hist[t + 6144];
        int h1 = hist[t + 1024] + hist[t + 3072] + hist[t + 5120] + hist[t + 7168];
        hist[t] = h0;
        hist[t + 1024] = h1;
    }
    __syncthreads();                             // merged hist ready

    int np = snp_s + sdnp;
    int k = np * 3;
    if (k > P_ - 1) k = P_ - 1;

    unsigned T = 0x7FFFFFFFu;                    // k==0: nothing > T, skrem 0
    if (k > 0) {                                 // k uniform -> no divergence
        if (wid == 0) scan_hist(hist, 2048, k, &sB[0], &sR[0]);
        __syncthreads();
        unsigned B1 = (unsigned)sB[0];
        int k1 = sR[0];
#pragma unroll
        for (int i = 0; i < 24; i++) {
            if (i < nel) {
                unsigned bb = __float_as_uint(xv[i]);
                if ((bb >> 20) == B1) atomicAdd(&hist2[(bb >> 10) & 0x3FF], 1);
            }
        }
        __syncthreads();
        if (wid == 0) scan_hist(hist2, 1024, k1, &sB[1], &sR[1]);
        __syncthreads();
        unsigned hi = (B1 << 10) | (unsigned)sB[1];
        int k2 = sR[1];
#pragma unroll
        for (int i = 0; i < 24; i++) {
            if (i < nel) {
                unsigned bb = __float_as_uint(xv[i]);
                if ((bb >> 10) == hi) atomicAdd(&hist3[bb & 0x3FF], 1);
            }
        }
        __syncthreads();
        if (wid == 0) scan_hist(hist3, 1024, k2, &sB[2], &sR[2]);
        __syncthreads();
        T = (hi << 10) | (unsigned)sB[2];
    }

    float psum = 0.0f;
    int cgt = 0;
#pragma unroll
    for (int i = 0; i < 24; i++) {
        if (__float_as_uint(xv[i]) > T) { psum += xv[i]; cgt++; }
    }
    for (int off = 32; off; off >>= 1) {
        psum += __shfl_down(psum, off);
        cgt += __shfl_down(cgt, off);
    }
    if (lane == 0) { wsum[wid] = psum; wcgt[wid] = cgt; }
    __syncthreads();
    if (t == 0) {
        float s2 = 0.0f;
        int cg = 0;
        for (int i = 0; i < 16; i++) { s2 += wsum[i]; cg += wcgt[i]; }
        int skrem = k - cg;                      // >= 0 by construction
        double tot = (double)s2 + (double)skrem * (double)__uint_as_float(T);
        bll[b] = (double)(sll_s + sdll);
        bpc[b] = (double)(spc_s + sdpce) + tot;
        bnp[b] = np;
    }
}

// kC: final 64-wide reduce.
__global__ void kC_final(const double* __restrict__ bll,
                         const double* __restrict__ bpc,
                         const int* __restrict__ bnp,
                         float* __restrict__ out) {
    int t = threadIdx.x;  // 64 threads
    double a = bll[t], c = bpc[t];
    int n = bnp[t];
    for (int off = 32; off; off >>= 1) {
        a += __shfl_down(a, off);
        c += __shfl_down(c, off);
        n += __shfl_down(n, off);
    }
    if (t == 0) {
        double dn = (double)n;
        out[0] = (float)(a / dn);
        out[1] = (float)(c / dn);
    }
}

// ---------------------------------------------------------------- launch

extern "C" void kernel_launch(void* const* d_in, const int* in_sizes, int n_in,
                              void* d_out, int out_size, void* d_ws, size_t ws_size,
                              hipStream_t stream) {
    const float* loc    = (const float*)d_in[0];
    const float* conf   = (const float*)d_in[1];
    const float* priors = (const float*)d_in[2];
    const float* truths = (const float*)d_in[3];
    const int*   labels = (const int*)d_in[4];
    float* out = (float*)d_out;

    char* ws = (char*)d_ws;
    // layout:
    //   [0       .. 786432)   part_key: 64*96*16 u64
    //   [786432  .. 811008)   part_ll:  96*64 floats
    //   [811008  .. 835584)   part_pce: 96*64 floats
    //   [835584  .. 860160)   part_np:  96*64 ints
    //   [860160  .. 860672)   bll: 64 doubles
    //   [860672  .. 861184)   bpc: 64 doubles
    //   [861184  .. 861440)   bnp: 64 ints
    //   [1048576 .. 7336960)  mine: B*P floats
    unsigned long long* part_key = (unsigned long long*)(ws);
    float*  part_ll  = (float*)(ws + 786432);
    float*  part_pce = (float*)(ws + 811008);
    int*    part_np  = (int*)(ws + 835584);
    double* bll      = (double*)(ws + 860160);
    double* bpc      = (double*)(ws + 860672);
    int*    bnp      = (int*)(ws + 861184);
    float*  mine     = (float*)(ws + 1048576);

    hipLaunchKernelGGL(kF_fused, dim3(NPL_, B_), dim3(256), 0, stream,
                       loc, conf, priors, truths, labels,
                       mine, part_ll, part_pce, part_np, part_key);
    hipLaunchKernelGGL(kB_batch, dim3(B_), dim3(1024), 0, stream,
                       loc, conf, priors, truths, labels, mine,
                       part_ll, part_pce, part_np, part_key, bll, bpc, bnp);
    hipLaunchKernelGGL(kC_final, dim3(1), dim3(64), 0, stream, bll, bpc, bnp, out);
}